// Round 2
// baseline (375.959 us; speedup 1.0000x reference)
//
#include <hip/hip_runtime.h>
#include <math.h>

#define BB 4
#define NN 8192
#define CC 256
#define OUTC 256
#define EE 262144
#define MROWS (BB*NN)   /* 32768 */

// ---------------- CSR build ----------------
// edge_index arrives as int32 (harness converts integer inputs to int32).

__global__ void count_edges(const int* __restrict__ ei, int* __restrict__ cnt) {
    int e = blockIdx.x * blockDim.x + threadIdx.x;
    int stride = gridDim.x * blockDim.x;
    for (; e < EE; e += stride) {
        int s = ei[e] & (NN - 1);          // src row; mask is a no-op for valid data
        atomicAdd(&cnt[s], 1);
    }
}

// single block of 1024 threads: exclusive scan of cnt[0..N) -> offs, plus inv_deg
__global__ void scan_deg(const int* __restrict__ cnt, int* __restrict__ offs,
                         float* __restrict__ invdeg) {
    __shared__ int sh[1024];
    int th = threadIdx.x;
    int base = th * 8;
    int local[8];
    int s = 0;
    for (int k = 0; k < 8; k++) { local[k] = cnt[base + k]; s += local[k]; }
    sh[th] = s;
    __syncthreads();
    for (int off = 1; off < 1024; off <<= 1) {
        int v = (th >= off) ? sh[th - off] : 0;
        __syncthreads();
        sh[th] += v;
        __syncthreads();
    }
    int run = (th == 0) ? 0 : sh[th - 1];
    for (int k = 0; k < 8; k++) {
        offs[base + k] = run;
        invdeg[base + k] = 1.0f / (float)(1 + local[k]);
        run += local[k];
    }
    if (th == 1023) offs[NN] = run;
}

__global__ void fill_adj(const int* __restrict__ ei, const int* __restrict__ offs,
                         int* __restrict__ fc, int* __restrict__ adj) {
    int e = blockIdx.x * blockDim.x + threadIdx.x;
    int stride = gridDim.x * blockDim.x;
    for (; e < EE; e += stride) {
        int s = ei[e] & (NN - 1);
        int d = ei[EE + e] & (NN - 1);
        int p = offs[s] + atomicAdd(&fc[s], 1);
        adj[p] = d;
    }
}

// ---------------- GEMM: X[32768,256] @ {W_self|W_neigh}[256,256] ----------------
// blockIdx.y in [0,8): col tiles 0..3 -> W_self -> Z (=d_out scratch), 4..7 -> W_neigh -> U (ws)

__global__ __launch_bounds__(256) void gemm_xw(const float* __restrict__ X,
                                               const float* __restrict__ Ws,
                                               const float* __restrict__ Wn,
                                               float* __restrict__ Z,
                                               float* __restrict__ U) {
    __shared__ float As[16][68];   // [kk][row], padded
    __shared__ float Bs[16][68];   // [kk][col], padded

    int tid = threadIdx.x;
    int row0 = blockIdx.x * 64;
    int ct = blockIdx.y;
    const float* W = (ct < 4) ? Ws : Wn;
    int col0 = (ct & 3) * 64;

    int arow = tid >> 2;          // 0..63
    int akk  = (tid & 3) * 4;     // 0,4,8,12
    int bkk  = tid >> 4;          // 0..15
    int bcc  = (tid & 15) * 4;    // 0..60
    int tx = tid & 15, ty = tid >> 4;

    float acc[4][4];
#pragma unroll
    for (int i = 0; i < 4; i++)
#pragma unroll
        for (int j = 0; j < 4; j++) acc[i][j] = 0.0f;

    for (int k0 = 0; k0 < CC; k0 += 16) {
        float4 av = *(const float4*)&X[(size_t)(row0 + arow) * CC + k0 + akk];
        float4 bv = *(const float4*)&W[(size_t)(k0 + bkk) * OUTC + col0 + bcc];
        As[akk + 0][arow] = av.x;
        As[akk + 1][arow] = av.y;
        As[akk + 2][arow] = av.z;
        As[akk + 3][arow] = av.w;
        *(float4*)&Bs[bkk][bcc] = bv;
        __syncthreads();
#pragma unroll
        for (int kk = 0; kk < 16; kk++) {
            float4 a = *(const float4*)&As[kk][ty * 4];
            float4 b = *(const float4*)&Bs[kk][tx * 4];
            acc[0][0] += a.x * b.x; acc[0][1] += a.x * b.y; acc[0][2] += a.x * b.z; acc[0][3] += a.x * b.w;
            acc[1][0] += a.y * b.x; acc[1][1] += a.y * b.y; acc[1][2] += a.y * b.z; acc[1][3] += a.y * b.w;
            acc[2][0] += a.z * b.x; acc[2][1] += a.z * b.y; acc[2][2] += a.z * b.z; acc[2][3] += a.z * b.w;
            acc[3][0] += a.w * b.x; acc[3][1] += a.w * b.y; acc[3][2] += a.w * b.z; acc[3][3] += a.w * b.w;
        }
        __syncthreads();
    }

    float* O = (ct < 4) ? Z : U;
#pragma unroll
    for (int i = 0; i < 4; i++) {
        int r = row0 + ty * 4 + i;
        float4 v = make_float4(acc[i][0], acc[i][1], acc[i][2], acc[i][3]);
        *(float4*)&O[(size_t)r * OUTC + col0 + tx * 4] = v;
    }
}

// ---------------- Aggregate + bias + GeLU ----------------
// one wave per (node i, batch b); wave id w = i*4 + b so the 4 waves of a block
// share node i's adjacency list (L1 reuse). lane handles channels lane*4..lane*4+3.

__global__ __launch_bounds__(256) void agg_gelu(const float* __restrict__ U,
                                                const float* __restrict__ invdeg,
                                                const int* __restrict__ offs,
                                                const int* __restrict__ adj,
                                                const float* __restrict__ bs,
                                                const float* __restrict__ bn,
                                                float* __restrict__ Out) {
    int w = (blockIdx.x * blockDim.x + threadIdx.x) >> 6;   // 0..32767
    int lane = threadIdx.x & 63;
    int b = w & 3;
    int i = w >> 2;
    int c = lane * 4;

    const float4* Ub = (const float4*)(U + (size_t)b * NN * CC);
    float4 acc = Ub[(size_t)i * 64 + lane];
    int p0 = offs[i], p1 = offs[i + 1];
    for (int p = p0; p < p1; p++) {
        int j = adj[p];
        float4 v = Ub[(size_t)j * 64 + lane];
        acc.x += v.x; acc.y += v.y; acc.z += v.z; acc.w += v.w;
    }
    float s = invdeg[i];

    size_t zoff = ((size_t)(b * NN + i) * CC + c);
    float4 z = *(const float4*)&Out[zoff];
    float4 vs = *(const float4*)&bs[c];
    float4 vn = *(const float4*)&bn[c];

    float v0 = z.x + vs.x + vn.x + s * acc.x;
    float v1 = z.y + vs.y + vn.y + s * acc.y;
    float v2 = z.z + vs.z + vn.z + s * acc.z;
    float v3 = z.w + vs.w + vn.w + s * acc.w;

    const float k = 0.70710678118654752f;
    float4 g;
    g.x = 0.5f * v0 * (1.0f + erff(v0 * k));
    g.y = 0.5f * v1 * (1.0f + erff(v1 * k));
    g.z = 0.5f * v2 * (1.0f + erff(v2 * k));
    g.w = 0.5f * v3 * (1.0f + erff(v3 * k));
    *(float4*)&Out[zoff] = g;
}

// ---------------- launch ----------------

extern "C" void kernel_launch(void* const* d_in, const int* in_sizes, int n_in,
                              void* d_out, int out_size, void* d_ws, size_t ws_size,
                              hipStream_t stream) {
    const float* x   = (const float*)d_in[0];
    const int* ei    = (const int*)d_in[1];       // int32! harness converts integer inputs
    const float* Ws  = (const float*)d_in[2];
    const float* bsv = (const float*)d_in[3];
    const float* Wn  = (const float*)d_in[4];
    const float* bnv = (const float*)d_in[5];
    float* out = (float*)d_out;

    char* ws = (char*)d_ws;
    size_t o = 0;
    float* U = (float*)(ws + o);      o += (size_t)MROWS * OUTC * 4;   // 32 MB
    int* cnt = (int*)(ws + o);        o += (size_t)NN * 4;
    int* fc  = (int*)(ws + o);        o += (size_t)NN * 4;
    int* offs = (int*)(ws + o);       o += (size_t)(NN + 1) * 4;
    o = (o + 255) & ~(size_t)255;
    float* invdeg = (float*)(ws + o); o += (size_t)NN * 4;
    int* adj = (int*)(ws + o);        o += (size_t)EE * 4;

    // zero cnt + fc (contiguous)
    hipMemsetAsync(cnt, 0, (size_t)NN * 8, stream);

    count_edges<<<256, 256, 0, stream>>>(ei, cnt);
    scan_deg<<<1, 1024, 0, stream>>>(cnt, offs, invdeg);
    fill_adj<<<256, 256, 0, stream>>>(ei, offs, fc, adj);

    gemm_xw<<<dim3(512, 8), 256, 0, stream>>>(x, Ws, Wn, out, U);

    agg_gelu<<<8192, 256, 0, stream>>>(U, invdeg, offs, adj, bsv, bnv, out);
}

// Round 3
// 272.889 us; speedup vs baseline: 1.3777x; 1.3777x over previous
//
#include <hip/hip_runtime.h>
#include <math.h>

#define BB 4
#define NN 8192
#define CC 256
#define OUTC 256
#define EE 262144
#define MROWS (BB*NN)   /* 32768 */

typedef __attribute__((ext_vector_type(8))) short short8;
typedef __attribute__((ext_vector_type(4))) float f32x4;

__device__ inline unsigned short f2bf(float f) {
    union { float f; unsigned u; } a; a.f = f;
    unsigned u = a.u;
    u += 0x7fffu + ((u >> 16) & 1u);   // RNE
    return (unsigned short)(u >> 16);
}
__device__ inline float bf2f(unsigned short h) {
    union { unsigned u; float f; } a; a.u = ((unsigned)h) << 16;
    return a.f;
}

// ---------------- CSR build (edge_index arrives as int32) ----------------

__global__ void count_edges(const int* __restrict__ ei, int* __restrict__ cnt) {
    int e = blockIdx.x * blockDim.x + threadIdx.x;
    int stride = gridDim.x * blockDim.x;
    for (; e < EE; e += stride) {
        int s = ei[e] & (NN - 1);
        atomicAdd(&cnt[s], 1);
    }
}

__global__ void scan_deg(const int* __restrict__ cnt, int* __restrict__ offs,
                         float* __restrict__ invdeg) {
    __shared__ int sh[1024];
    int th = threadIdx.x;
    int base = th * 8;
    int local[8];
    int s = 0;
    for (int k = 0; k < 8; k++) { local[k] = cnt[base + k]; s += local[k]; }
    sh[th] = s;
    __syncthreads();
    for (int off = 1; off < 1024; off <<= 1) {
        int v = (th >= off) ? sh[th - off] : 0;
        __syncthreads();
        sh[th] += v;
        __syncthreads();
    }
    int run = (th == 0) ? 0 : sh[th - 1];
    for (int k = 0; k < 8; k++) {
        offs[base + k] = run;
        invdeg[base + k] = 1.0f / (float)(1 + local[k]);
        run += local[k];
    }
    if (th == 1023) offs[NN] = run;
}

__global__ void fill_adj(const int* __restrict__ ei, const int* __restrict__ offs,
                         int* __restrict__ fc, int* __restrict__ adj) {
    int e = blockIdx.x * blockDim.x + threadIdx.x;
    int stride = gridDim.x * blockDim.x;
    for (; e < EE; e += stride) {
        int s = ei[e] & (NN - 1);
        int d = ei[EE + e] & (NN - 1);
        int p = offs[s] + atomicAdd(&fc[s], 1);
        adj[p] = d;
    }
}

// ---------------- W transpose + bf16 cast: Wt[n][k], n in [0,512) ----------------

__global__ __launch_bounds__(256) void prep_w(const float* __restrict__ Ws,
                                              const float* __restrict__ Wn,
                                              unsigned short* __restrict__ Wt) {
    int n = blockIdx.x;          // 0..511
    int k = threadIdx.x;         // 0..255
    const float* W = (n < 256) ? Ws : Wn;
    int c = n & 255;
    Wt[(size_t)n * 256 + k] = f2bf(W[(size_t)k * 256 + c]);
}

// ---------------- MFMA GEMM: X[32768,256]fp32 -> bf16 staged; Wt bf16 ----------------
// 128x128 tile, BK=32, 4 waves (2x2), 4x4 of 16x16x32 MFMA per wave.
// cols 0..255 (blockIdx.y 0,1) -> Z fp32 in d_out; cols 256..511 (y 2,3) -> U bf16.

#define LDK 40   /* padded LDS row stride (elements); 80B = 16B-aligned, 2-way-max banks */

__global__ __launch_bounds__(256) void gemm_mfma(const float* __restrict__ X,
                                                 const unsigned short* __restrict__ Wt,
                                                 float* __restrict__ Z,
                                                 unsigned short* __restrict__ U) {
    __shared__ unsigned short sA[128 * LDK];
    __shared__ unsigned short sB[128 * LDK];
    int tid = threadIdx.x;
    int wave = tid >> 6, lane = tid & 63;
    int row0 = blockIdx.x * 128;
    int col0 = blockIdx.y * 128;       // global col in [0,512)
    int wm = wave & 1, wn = wave >> 1;

    f32x4 acc[4][4];
#pragma unroll
    for (int i = 0; i < 4; i++)
#pragma unroll
        for (int j = 0; j < 4; j++) acc[i][j] = (f32x4)0.0f;

    int srow = tid >> 2;          // 0..63
    int skoff = (tid & 3) * 8;    // 0,8,16,24

    for (int k0 = 0; k0 < CC; k0 += 32) {
#pragma unroll
        for (int q = 0; q < 2; q++) {
            int rr = q * 64 + srow;
            const float* src = &X[(size_t)(row0 + rr) * CC + k0 + skoff];
            float4 v0 = *(const float4*)src;
            float4 v1 = *(const float4*)(src + 4);
            short8 t;
            t[0] = (short)f2bf(v0.x); t[1] = (short)f2bf(v0.y);
            t[2] = (short)f2bf(v0.z); t[3] = (short)f2bf(v0.w);
            t[4] = (short)f2bf(v1.x); t[5] = (short)f2bf(v1.y);
            t[6] = (short)f2bf(v1.z); t[7] = (short)f2bf(v1.w);
            *(short8*)&sA[rr * LDK + skoff] = t;
        }
#pragma unroll
        for (int q = 0; q < 2; q++) {
            int nn = q * 64 + srow;
            short8 v = *(const short8*)&Wt[(size_t)(col0 + nn) * CC + k0 + skoff];
            *(short8*)&sB[nn * LDK + skoff] = v;
        }
        __syncthreads();

        short8 af[4], bfr[4];
        int am = wm * 64 + (lane & 15);
        int ak = (lane >> 4) * 8;
#pragma unroll
        for (int mi = 0; mi < 4; mi++)
            af[mi] = *(const short8*)&sA[(am + mi * 16) * LDK + ak];
        int bn = wn * 64 + (lane & 15);
#pragma unroll
        for (int ni = 0; ni < 4; ni++)
            bfr[ni] = *(const short8*)&sB[(bn + ni * 16) * LDK + ak];
#pragma unroll
        for (int mi = 0; mi < 4; mi++)
#pragma unroll
            for (int ni = 0; ni < 4; ni++)
                acc[mi][ni] = __builtin_amdgcn_mfma_f32_16x16x32_bf16(
                    af[mi], bfr[ni], acc[mi][ni], 0, 0, 0);
        __syncthreads();
    }

    // epilogue: D[row,col] with row=(lane>>4)*4+r, col=lane&15  (m89/m91-verified)
    int rbase = row0 + wm * 64 + (lane >> 4) * 4;
    int cbase = col0 + wn * 64 + (lane & 15);
#pragma unroll
    for (int mi = 0; mi < 4; mi++) {
#pragma unroll
        for (int ni = 0; ni < 4; ni++) {
            int cc = cbase + ni * 16;
#pragma unroll
            for (int r = 0; r < 4; r++) {
                int rr = rbase + mi * 16 + r;
                float v = acc[mi][ni][r];
                if (col0 < 256) Z[(size_t)rr * 256 + cc] = v;
                else            U[(size_t)rr * 256 + (cc - 256)] = f2bf(v);
            }
        }
    }
}

// ---------------- Aggregate + bias + GeLU (bf16 gathers) ----------------
// blockIdx%8 -> (batch, half) so each XCD (heuristically blk%8) touches ONE
// 4 MB batch slab of U == its L2. Z/out/adj streamed nontemporally.

__global__ __launch_bounds__(256) void agg_gelu(const unsigned short* __restrict__ U,
                                                const float* __restrict__ invdeg,
                                                const int* __restrict__ offs,
                                                const int* __restrict__ adj,
                                                const float* __restrict__ bs,
                                                const float* __restrict__ bn,
                                                float* __restrict__ Out) {
    int r = blockIdx.x & 7;
    int q = blockIdx.x >> 3;              // 0..1023
    int b = r & 3;
    int g = ((r >> 2) << 10) + q;         // 0..2047
    int i = (g << 2) + (threadIdx.x >> 6);
    int lane = threadIdx.x & 63;
    int c = lane * 4;

    const unsigned short* Ub = U + (size_t)b * NN * 256;

    ushort4 sv = *(const ushort4*)&Ub[(size_t)i * 256 + c];
    float a0 = bf2f(sv.x), a1 = bf2f(sv.y), a2 = bf2f(sv.z), a3 = bf2f(sv.w);

    int p0 = offs[i], p1 = offs[i + 1];
    for (int p = p0; p < p1; p++) {
        int j = __builtin_nontemporal_load(&adj[p]);
        ushort4 v = *(const ushort4*)&Ub[(size_t)j * 256 + c];
        a0 += bf2f(v.x); a1 += bf2f(v.y); a2 += bf2f(v.z); a3 += bf2f(v.w);
    }
    float s = invdeg[i];

    size_t zoff = (size_t)(b * NN + i) * 256 + c;
    float z0 = __builtin_nontemporal_load(&Out[zoff + 0]);
    float z1 = __builtin_nontemporal_load(&Out[zoff + 1]);
    float z2 = __builtin_nontemporal_load(&Out[zoff + 2]);
    float z3 = __builtin_nontemporal_load(&Out[zoff + 3]);
    float4 vs = *(const float4*)&bs[c];
    float4 vn = *(const float4*)&bn[c];

    float v0 = z0 + vs.x + vn.x + s * a0;
    float v1 = z1 + vs.y + vn.y + s * a1;
    float v2 = z2 + vs.z + vn.z + s * a2;
    float v3 = z3 + vs.w + vn.w + s * a3;

    const float k = 0.70710678118654752f;
    __builtin_nontemporal_store(0.5f * v0 * (1.0f + erff(v0 * k)), &Out[zoff + 0]);
    __builtin_nontemporal_store(0.5f * v1 * (1.0f + erff(v1 * k)), &Out[zoff + 1]);
    __builtin_nontemporal_store(0.5f * v2 * (1.0f + erff(v2 * k)), &Out[zoff + 2]);
    __builtin_nontemporal_store(0.5f * v3 * (1.0f + erff(v3 * k)), &Out[zoff + 3]);
}

// ---------------- launch ----------------

extern "C" void kernel_launch(void* const* d_in, const int* in_sizes, int n_in,
                              void* d_out, int out_size, void* d_ws, size_t ws_size,
                              hipStream_t stream) {
    const float* x   = (const float*)d_in[0];
    const int* ei    = (const int*)d_in[1];       // int32 (harness converts ints)
    const float* Ws  = (const float*)d_in[2];
    const float* bsv = (const float*)d_in[3];
    const float* Wn  = (const float*)d_in[4];
    const float* bnv = (const float*)d_in[5];
    float* out = (float*)d_out;

    char* ws = (char*)d_ws;
    size_t o = 0;
    unsigned short* U  = (unsigned short*)(ws + o); o += (size_t)MROWS * OUTC * 2;  // 16 MB
    unsigned short* Wt = (unsigned short*)(ws + o); o += (size_t)512 * 256 * 2;     // 256 KB
    int* cnt  = (int*)(ws + o);   o += (size_t)NN * 4;
    int* fc   = (int*)(ws + o);   o += (size_t)NN * 4;
    int* offs = (int*)(ws + o);   o += (size_t)(NN + 1) * 4;
    o = (o + 255) & ~(size_t)255;
    float* invdeg = (float*)(ws + o); o += (size_t)NN * 4;
    int* adj  = (int*)(ws + o);   o += (size_t)EE * 4;

    hipMemsetAsync(cnt, 0, (size_t)NN * 8, stream);   // cnt + fc contiguous

    count_edges<<<256, 256, 0, stream>>>(ei, cnt);
    scan_deg<<<1, 1024, 0, stream>>>(cnt, offs, invdeg);
    fill_adj<<<256, 256, 0, stream>>>(ei, offs, fc, adj);

    prep_w<<<512, 256, 0, stream>>>(Ws, Wn, Wt);
    gemm_mfma<<<dim3(256, 4), 256, 0, stream>>>(x, Wt, out, U);

    agg_gelu<<<8192, 256, 0, stream>>>(U, invdeg, offs, adj, bsv, bnv, out);
}

// Round 4
// 210.254 us; speedup vs baseline: 1.7881x; 1.2979x over previous
//
#include <hip/hip_runtime.h>
#include <math.h>

#define BB 4
#define NN 8192
#define CC 256
#define OUTC 256
#define EE 262144
#define MROWS (BB*NN)   /* 32768 */

typedef __attribute__((ext_vector_type(8))) short short8;
typedef __attribute__((ext_vector_type(4))) float f32x4;

__device__ inline unsigned short f2bf(float f) {
    union { float f; unsigned u; } a; a.f = f;
    unsigned u = a.u;
    u += 0x7fffu + ((u >> 16) & 1u);   // RNE
    return (unsigned short)(u >> 16);
}
__device__ inline float bf2f(unsigned short h) {
    union { unsigned u; float f; } a; a.u = ((unsigned)h) << 16;
    return a.f;
}

// ---------------- CSR build (edge_index arrives as int32) ----------------

__global__ void count_edges(const int* __restrict__ ei, int* __restrict__ cnt) {
    int e = blockIdx.x * blockDim.x + threadIdx.x;
    int stride = gridDim.x * blockDim.x;
    for (; e < EE; e += stride) {
        int s = ei[e] & (NN - 1);
        atomicAdd(&cnt[s], 1);
    }
}

__global__ void scan_deg(const int* __restrict__ cnt, int* __restrict__ offs,
                         float* __restrict__ invdeg) {
    __shared__ int sh[1024];
    int th = threadIdx.x;
    int base = th * 8;
    int local[8];
    int s = 0;
    for (int k = 0; k < 8; k++) { local[k] = cnt[base + k]; s += local[k]; }
    sh[th] = s;
    __syncthreads();
    for (int off = 1; off < 1024; off <<= 1) {
        int v = (th >= off) ? sh[th - off] : 0;
        __syncthreads();
        sh[th] += v;
        __syncthreads();
    }
    int run = (th == 0) ? 0 : sh[th - 1];
    for (int k = 0; k < 8; k++) {
        offs[base + k] = run;
        invdeg[base + k] = 1.0f / (float)(1 + local[k]);
        run += local[k];
    }
    if (th == 1023) offs[NN] = run;
}

__global__ void fill_adj(const int* __restrict__ ei, const int* __restrict__ offs,
                         int* __restrict__ fc, int* __restrict__ adj) {
    int e = blockIdx.x * blockDim.x + threadIdx.x;
    int stride = gridDim.x * blockDim.x;
    for (; e < EE; e += stride) {
        int s = ei[e] & (NN - 1);
        int d = ei[EE + e] & (NN - 1);
        int p = offs[s] + atomicAdd(&fc[s], 1);
        adj[p] = d;
    }
}

// ---------------- W transpose + bf16 cast: Wt[n][k], n in [0,512) ----------------

__global__ __launch_bounds__(256) void prep_w(const float* __restrict__ Ws,
                                              const float* __restrict__ Wn,
                                              unsigned short* __restrict__ Wt) {
    int n = blockIdx.x;          // 0..511
    int k = threadIdx.x;         // 0..255
    const float* W = (n < 256) ? Ws : Wn;
    int c = n & 255;
    Wt[(size_t)n * 256 + k] = f2bf(W[(size_t)k * 256 + c]);
}

// ---------------- barrier-free MFMA GEMM ----------------
// 512 blocks: block = 64-row stripe of X. Stage A (64x256 bf16) to LDS ONCE
// (single __syncthreads in the kernel). Wave w owns cols w*128..+127; B
// fragments read straight from Wt (256 KB, L2-resident per XCD) — no B-tile
// staging, no K-loop barriers. X read exactly once (33.5 MB vs 134 MB before).

#define APAD 8
#define ALD (256 + APAD)   /* 264: 16-rows x 528B stride -> worst 2-way banks (free, m136) */

__global__ __launch_bounds__(256) void gemm_mfma(const float* __restrict__ X,
                                                 const unsigned short* __restrict__ Wt,
                                                 float* __restrict__ Z,
                                                 unsigned short* __restrict__ U) {
    __shared__ unsigned short sA[64 * ALD];
    int tid = threadIdx.x;
    int wave = tid >> 6, lane = tid & 63;
    int row0 = blockIdx.x * 64;

    // ---- stage A stripe: fp32 -> bf16, 64 B contiguous per thread per pass
#pragma unroll
    for (int qq = 0; qq < 4; qq++) {
        int f = qq * 4096 + tid * 16;   // flat element index in 64x256
        int rr = f >> 8, k0 = f & 255;
        const float* src = &X[(size_t)(row0 + rr) * 256 + k0];
        float4 u0 = *(const float4*)(src);
        float4 u1 = *(const float4*)(src + 4);
        float4 u2 = *(const float4*)(src + 8);
        float4 u3 = *(const float4*)(src + 12);
        short8 t0, t1;
        t0[0] = (short)f2bf(u0.x); t0[1] = (short)f2bf(u0.y);
        t0[2] = (short)f2bf(u0.z); t0[3] = (short)f2bf(u0.w);
        t0[4] = (short)f2bf(u1.x); t0[5] = (short)f2bf(u1.y);
        t0[6] = (short)f2bf(u1.z); t0[7] = (short)f2bf(u1.w);
        t1[0] = (short)f2bf(u2.x); t1[1] = (short)f2bf(u2.y);
        t1[2] = (short)f2bf(u2.z); t1[3] = (short)f2bf(u2.w);
        t1[4] = (short)f2bf(u3.x); t1[5] = (short)f2bf(u3.y);
        t1[6] = (short)f2bf(u3.z); t1[7] = (short)f2bf(u3.w);
        *(short8*)&sA[rr * ALD + k0] = t0;
        *(short8*)&sA[rr * ALD + k0 + 8] = t1;
    }
    __syncthreads();   // the only barrier

    int qrow = lane >> 4;      // quad 0..3 -> k-slice
    int fr = lane & 15;        // fragment row/col index

#pragma unroll
    for (int sp = 0; sp < 2; sp++) {
        int colbase = wave * 128 + sp * 64;     // global col in [0,512)
        f32x4 acc[4][4];
#pragma unroll
        for (int mi = 0; mi < 4; mi++)
#pragma unroll
            for (int ni = 0; ni < 4; ni++) acc[mi][ni] = (f32x4)0.0f;

        for (int k0 = 0; k0 < 256; k0 += 32) {
            int ak = k0 + qrow * 8;
            short8 af[4], bfr[4];
#pragma unroll
            for (int mi = 0; mi < 4; mi++)
                af[mi] = *(const short8*)&sA[(mi * 16 + fr) * ALD + ak];
#pragma unroll
            for (int ni = 0; ni < 4; ni++)
                bfr[ni] = *(const short8*)&Wt[(size_t)(colbase + ni * 16 + fr) * 256 + ak];
#pragma unroll
            for (int mi = 0; mi < 4; mi++)
#pragma unroll
                for (int ni = 0; ni < 4; ni++)
                    acc[mi][ni] = __builtin_amdgcn_mfma_f32_16x16x32_bf16(
                        af[mi], bfr[ni], acc[mi][ni], 0, 0, 0);
        }

        // epilogue: D row = quad*4 + r, col = lane&15 (m89/m91-verified)
#pragma unroll
        for (int mi = 0; mi < 4; mi++) {
            int rbase = row0 + mi * 16 + qrow * 4;
#pragma unroll
            for (int ni = 0; ni < 4; ni++) {
                int cc = colbase + ni * 16 + fr;
#pragma unroll
                for (int r = 0; r < 4; r++) {
                    float v = acc[mi][ni][r];
                    size_t rr = (size_t)(rbase + r);
                    if (colbase < 256) Z[rr * 256 + cc] = v;
                    else               U[rr * 256 + (cc - 256)] = f2bf(v);
                }
            }
        }
    }
}

// ---------------- Aggregate + bias + GeLU (bf16 gathers, 4x unrolled) ----------------
// blockIdx%8 -> (batch, half): each XCD sees one 4 MB batch slab of U (its L2).
// Gather loop unrolled x4: adj reads are wave-uniform (s_load), 4 independent
// row gathers in flight -> 4x memory-level parallelism vs round-3.

__global__ __launch_bounds__(256) void agg_gelu(const unsigned short* __restrict__ U,
                                                const float* __restrict__ invdeg,
                                                const int* __restrict__ offs,
                                                const int* __restrict__ adj,
                                                const float* __restrict__ bs,
                                                const float* __restrict__ bn,
                                                float* __restrict__ Out) {
    int r = blockIdx.x & 7;
    int q = blockIdx.x >> 3;              // 0..1023
    int b = r & 3;
    int g = ((r >> 2) << 10) + q;         // 0..2047
    int i = (g << 2) + (threadIdx.x >> 6);
    int lane = threadIdx.x & 63;
    int c = lane * 4;

    const unsigned short* Urow = U + (size_t)b * NN * 256 + c;

    // hoisted streams: z, biases (overlap with gathers)
    size_t zoff = (size_t)(b * NN + i) * 256 + c;
    float z0 = __builtin_nontemporal_load(&Out[zoff + 0]);
    float z1 = __builtin_nontemporal_load(&Out[zoff + 1]);
    float z2 = __builtin_nontemporal_load(&Out[zoff + 2]);
    float z3 = __builtin_nontemporal_load(&Out[zoff + 3]);
    float4 vs = *(const float4*)&bs[c];
    float4 vn = *(const float4*)&bn[c];

    ushort4 sv = *(const ushort4*)&Urow[(size_t)i * 256];
    float a0 = bf2f(sv.x), a1 = bf2f(sv.y), a2 = bf2f(sv.z), a3 = bf2f(sv.w);

    int p0 = offs[i], p1 = offs[i + 1];
    int p = p0;
    for (; p + 4 <= p1; p += 4) {
        int j0 = adj[p + 0];              // wave-uniform -> scalar loads
        int j1 = adj[p + 1];
        int j2 = adj[p + 2];
        int j3 = adj[p + 3];
        ushort4 v0 = *(const ushort4*)&Urow[(size_t)j0 * 256];
        ushort4 v1 = *(const ushort4*)&Urow[(size_t)j1 * 256];
        ushort4 v2 = *(const ushort4*)&Urow[(size_t)j2 * 256];
        ushort4 v3 = *(const ushort4*)&Urow[(size_t)j3 * 256];
        a0 += bf2f(v0.x); a1 += bf2f(v0.y); a2 += bf2f(v0.z); a3 += bf2f(v0.w);
        a0 += bf2f(v1.x); a1 += bf2f(v1.y); a2 += bf2f(v1.z); a3 += bf2f(v1.w);
        a0 += bf2f(v2.x); a1 += bf2f(v2.y); a2 += bf2f(v2.z); a3 += bf2f(v2.w);
        a0 += bf2f(v3.x); a1 += bf2f(v3.y); a2 += bf2f(v3.z); a3 += bf2f(v3.w);
    }
    for (; p < p1; p++) {
        int j = adj[p];
        ushort4 v = *(const ushort4*)&Urow[(size_t)j * 256];
        a0 += bf2f(v.x); a1 += bf2f(v.y); a2 += bf2f(v.z); a3 += bf2f(v.w);
    }
    float s = invdeg[i];

    float v0 = z0 + vs.x + vn.x + s * a0;
    float v1 = z1 + vs.y + vn.y + s * a1;
    float v2 = z2 + vs.z + vn.z + s * a2;
    float v3 = z3 + vs.w + vn.w + s * a3;

    const float k = 0.70710678118654752f;
    __builtin_nontemporal_store(0.5f * v0 * (1.0f + erff(v0 * k)), &Out[zoff + 0]);
    __builtin_nontemporal_store(0.5f * v1 * (1.0f + erff(v1 * k)), &Out[zoff + 1]);
    __builtin_nontemporal_store(0.5f * v2 * (1.0f + erff(v2 * k)), &Out[zoff + 2]);
    __builtin_nontemporal_store(0.5f * v3 * (1.0f + erff(v3 * k)), &Out[zoff + 3]);
}

// ---------------- launch ----------------

extern "C" void kernel_launch(void* const* d_in, const int* in_sizes, int n_in,
                              void* d_out, int out_size, void* d_ws, size_t ws_size,
                              hipStream_t stream) {
    const float* x   = (const float*)d_in[0];
    const int* ei    = (const int*)d_in[1];       // int32 (harness converts ints)
    const float* Ws  = (const float*)d_in[2];
    const float* bsv = (const float*)d_in[3];
    const float* Wn  = (const float*)d_in[4];
    const float* bnv = (const float*)d_in[5];
    float* out = (float*)d_out;

    char* ws = (char*)d_ws;
    size_t o = 0;
    unsigned short* U  = (unsigned short*)(ws + o); o += (size_t)MROWS * OUTC * 2;  // 16 MB
    unsigned short* Wt = (unsigned short*)(ws + o); o += (size_t)512 * 256 * 2;     // 256 KB
    int* cnt  = (int*)(ws + o);   o += (size_t)NN * 4;
    int* fc   = (int*)(ws + o);   o += (size_t)NN * 4;
    int* offs = (int*)(ws + o);   o += (size_t)(NN + 1) * 4;
    o = (o + 255) & ~(size_t)255;
    float* invdeg = (float*)(ws + o); o += (size_t)NN * 4;
    int* adj  = (int*)(ws + o);   o += (size_t)EE * 4;

    hipMemsetAsync(cnt, 0, (size_t)NN * 8, stream);   // cnt + fc contiguous

    count_edges<<<256, 256, 0, stream>>>(ei, cnt);
    scan_deg<<<1, 1024, 0, stream>>>(cnt, offs, invdeg);
    fill_adj<<<256, 256, 0, stream>>>(ei, offs, fc, adj);

    prep_w<<<512, 256, 0, stream>>>(Ws, Wn, Wt);
    gemm_mfma<<<512, 256, 0, stream>>>(x, Wt, out, U);

    agg_gelu<<<8192, 256, 0, stream>>>(U, invdeg, offs, adj, bsv, bnv, out);
}